// Round 9
// baseline (528.724 us; speedup 1.0000x reference)
//
#include <hip/hip_runtime.h>
#include <math.h>

#define B_ 2
#define N_ 400
#define F_ 246
#define C_ 32
#define LBL_ 1440

#define KX_ 320   // concat row: 246 x | 32 aggi | 32 aggj | 10 zero-pad
#define KN_ 256   // XNEW padded 246 -> 256

#define GRID_ 512 // exactly 2 blocks/CU x 256 CU (launch_bounds guarantees fit)
#define TPB_  256

#define T_ABUF (800 * KX_)
#define T_W2T  (64 * KX_)
#define T_WNT  (256 * KX_)
#define T_WOT  (LBL_ * KN_)

typedef __attribute__((ext_vector_type(8))) short bf16x8;  // 8 bf16, 4 VGPRs
typedef __attribute__((ext_vector_type(4))) float f32x4;

__device__ __forceinline__ short f2bf(float f) {           // RNE fp32->bf16
    unsigned u = __float_as_uint(f);
    return (short)((u + 0x7FFF + ((u >> 16) & 1)) >> 16);
}

struct KP {
    const float *x, *a, *e, *Ws, *bs, *al, *Wai, *bai, *Waj, *baj, *Wn, *bn, *Wo, *bo;
    float *out, *PQ;
    short *Abuf, *W2T, *WnT, *WoT, *XN16;
    int *bar;   // bar[0]=cnt, bar[1]=gen  (zeroed by k_zero every launch)
};

// Capture-safe grid barrier. Monotone generation: barrier #it waits for
// gen > it. AGENT scope acq/rel gives cross-XCD visibility of all normal
// stores made before arrival (G16). cnt reset ordered before gen release.
__device__ __forceinline__ void gbar(int* cnt, int* gen, int it) {
    __syncthreads();
    if (threadIdx.x == 0) {
        if (__hip_atomic_fetch_add(cnt, 1, __ATOMIC_ACQ_REL,
                                   __HIP_MEMORY_SCOPE_AGENT) == GRID_ - 1) {
            __hip_atomic_store(cnt, 0, __ATOMIC_RELAXED, __HIP_MEMORY_SCOPE_AGENT);
            __hip_atomic_store(gen, it + 1, __ATOMIC_RELEASE, __HIP_MEMORY_SCOPE_AGENT);
        } else {
            while (__hip_atomic_load(gen, __ATOMIC_ACQUIRE,
                                     __HIP_MEMORY_SCOPE_AGENT) <= it)
                __builtin_amdgcn_s_sleep(2);
        }
    }
    __syncthreads();
}

__global__ void k_zero(int* bar) {
    if (threadIdx.x < 2) bar[threadIdx.x] = 0;
}

// 16x16 MFMA tile: C = A[m0:+16,:K] * BT[n0:+16,:K]^T. Row-major bf16,
// K mult of 32. Layouts (HW-verified m89/m120): A[m=lane&15][k=quad*8+j];
// BT row n, consecutive k -> one 16B load; C/D col=lane&15, row=quad*4+reg.
template <int K>
__device__ __forceinline__ f32x4 mfma_tile(const short* __restrict__ A,
                                           const short* __restrict__ BT,
                                           int m0, int n0, int lane) {
    int r = lane & 15, quad = lane >> 4;
    const short* ap = A + (size_t)(m0 + r) * K + quad * 8;
    const short* bp = BT + (size_t)(n0 + r) * K + quad * 8;
    f32x4 acc = {0.f, 0.f, 0.f, 0.f};
    #pragma unroll
    for (int kk = 0; kk < K; kk += 32) {
        bf16x8 av = *(const bf16x8*)(ap + kk);
        bf16x8 bv = *(const bf16x8*)(bp + kk);
        acc = __builtin_amdgcn_mfma_f32_16x16x32_bf16(av, bv, acc, 0, 0, 0);
    }
    return acc;
}

__global__ __launch_bounds__(TPB_, 2) void k_fused(KP p) {
    int tid  = threadIdx.x;
    int gt   = blockIdx.x * TPB_ + tid;       // global thread id
    int wv   = gt >> 6;                       // global wave id
    int lane = tid & 63;
    const int NT = GRID_ * TPB_;              // 131072 threads
    const int NW = NT / 64;                   // 2048 waves
    int* cnt = p.bar;
    int* gen = p.bar + 1;

    // ---- phase 1: bf16 staging (all reads coalesced; 2B writes may stride) --
    // Abuf[800][320] x-part (+zero pad; agg cols overwritten in phase 3)
    for (int t = gt; t < T_ABUF; t += NT) {
        int row = t / KX_, k = t % KX_;
        p.Abuf[t] = (k < F_) ? f2bf(p.x[row * F_ + k]) : (short)0;
    }
    // W2T[64][320]: n<32 -> Ws[k][n] (P); n>=32 -> Ws[246+k][n-32] (Q)
    for (int t = gt; t < T_W2T; t += NT) {
        int n = t & 63, k = t >> 6;           // n fast -> coalesced Ws read
        float v = 0.f;
        if (k < F_) v = (n < C_) ? p.Ws[k * C_ + n] : p.Ws[(F_ + k) * C_ + (n - C_)];
        p.W2T[(size_t)n * KX_ + k] = f2bf(v);
    }
    // WnT[256][320] = W_node^T zero-padded
    for (int t = gt; t < T_WNT; t += NT) {
        int n = t & 255, k = t >> 8;          // n fast -> coalesced Wn read
        float v = (n < F_ && k < F_ + 2 * C_) ? p.Wn[k * F_ + n] : 0.f;
        p.WnT[(size_t)n * KX_ + k] = f2bf(v);
    }
    // WoT[1440][256] = W_out^T
    for (int t = gt; t < T_WOT; t += NT) {
        int n = t % LBL_, k = t / LBL_;       // n fast -> coalesced Wo read
        p.WoT[(size_t)n * KN_ + k] = (k < F_) ? f2bf(p.Wo[k * LBL_ + n]) : (short)0;
    }
    gbar(cnt, gen, 0);

    // ---- phase 2: PQ[800][64] = x @ [WsP | WsQ]  (fp32) ------------------
    for (int t = wv; t < 50 * 4; t += NW) {
        int m0 = (t % 50) * 16, n0 = (t / 50) * 16;
        f32x4 acc = mfma_tile<KX_>(p.Abuf, p.W2T, m0, n0, lane);
        int n = n0 + (lane & 15), mb = m0 + (lane >> 4) * 4;
        #pragma unroll
        for (int r = 0; r < 4; ++r)
            p.PQ[(size_t)(mb + r) * 64 + n] = acc[r];
    }
    gbar(cnt, gen, 1);

    // ---- phase 3: aggregation (sparse, fp32 VALU) -> bf16 agg cols of Abuf --
    {
        __shared__ float part[8][C_ + 1];
        int c = tid & 31, g = tid >> 5;
        for (int v = blockIdx.x; v < 2 * B_ * N_; v += GRID_) {
            int mode = (v >= B_ * N_) ? 1 : 0;
            int row  = mode ? v - B_ * N_ : v;
            int b = row / N_, n = row % N_;

            float w3  = p.Ws[(2 * F_) * C_ + c];
            float w4  = p.Ws[(2 * F_ + 1) * C_ + c];
            float bsc = p.bs[c];
            float alc = p.al[c];
            float wat = mode ? p.Waj[c] : p.Wai[c];
            float bat = mode ? p.baj[0] : p.bai[0];

            float ownc = p.PQ[(size_t)row * 64 + (mode ? 32 : 0) + c];
            const float* oth = p.PQ + (size_t)b * N_ * 64 + (mode ? 0 : 32) + c;
            const float* abase = p.a + (size_t)b * N_ * N_;
            const float* ebase = p.e + (size_t)b * N_ * N_;

            float acc = 0.f;
            #pragma unroll 4
            for (int m = g; m < N_; m += 8) {
                float aij  = mode ? abase[m * N_ + n] : abase[n * N_ + m];
                float er   = ebase[n * N_ + m];
                float ec   = ebase[m * N_ + n];
                float othv = oth[(size_t)m * 64];
                if (aij != 0.f) {                 // uniform per 32-lane group
                    float eij = mode ? ec : er;
                    float eji = mode ? er : ec;
                    float raw = ownc + othv + eij * w3 + eji * w4 + bsc;
                    float s = (raw >= 0.f ? raw : alc * raw) * aij;
                    float t2 = s * wat;           // 32-ch butterfly dot
                    t2 += __shfl_xor(t2, 1, 32);
                    t2 += __shfl_xor(t2, 2, 32);
                    t2 += __shfl_xor(t2, 4, 32);
                    t2 += __shfl_xor(t2, 8, 32);
                    t2 += __shfl_xor(t2, 16, 32);
                    float att = 1.f / (1.f + __expf(-(t2 + bat)));
                    acc += s * att;
                }
            }
            part[g][c] = acc;
            __syncthreads();
            if (tid < C_) {
                float tot = 0.f;
                #pragma unroll
                for (int gg = 0; gg < 8; ++gg) tot += part[gg][tid];
                // Abuf agg cols: mode 0 -> 246..277 (agg_i), 1 -> 278..309
                p.Abuf[(size_t)row * KX_ + F_ + mode * C_ + tid] = f2bf(tot);
            }
            __syncthreads();
        }
    }
    gbar(cnt, gen, 2);

    // ---- phase 4: XN16[800][256] = bf16(Abuf @ WnT^T + bn) ---------------
    for (int t = wv; t < 50 * 16; t += NW) {
        int m0 = (t % 50) * 16, n0 = (t / 50) * 16;
        f32x4 acc = mfma_tile<KX_>(p.Abuf, p.WnT, m0, n0, lane);
        int n = n0 + (lane & 15), mb = m0 + (lane >> 4) * 4;
        float bv = (n < F_) ? p.bn[n] : 0.f;
        #pragma unroll
        for (int r = 0; r < 4; ++r)
            p.XN16[(size_t)(mb + r) * KN_ + n] =
                (n < F_) ? f2bf(acc[r] + bv) : (short)0;
    }
    gbar(cnt, gen, 3);

    // ---- phase 5: out[800][1440] = XN16 @ WoT^T + bo  (fp32) -------------
    for (int t = wv; t < 50 * 90; t += NW) {
        int m0 = (t % 50) * 16, n0 = (t / 50) * 16;
        f32x4 acc = mfma_tile<KN_>(p.XN16, p.WoT, m0, n0, lane);
        int n = n0 + (lane & 15), mb = m0 + (lane >> 4) * 4;
        float bv = p.bo[n];
        #pragma unroll
        for (int r = 0; r < 4; ++r)
            p.out[(size_t)(mb + r) * LBL_ + n] = acc[r] + bv;
    }
}

// ---------------------------------------------------------------------------
extern "C" void kernel_launch(void* const* d_in, const int* in_sizes, int n_in,
                              void* d_out, int out_size, void* d_ws, size_t ws_size,
                              hipStream_t stream) {
    KP p;
    p.x   = (const float*)d_in[0];
    p.a   = (const float*)d_in[1];
    p.e   = (const float*)d_in[2];
    p.Ws  = (const float*)d_in[3];
    p.bs  = (const float*)d_in[4];
    p.al  = (const float*)d_in[5];
    p.Wai = (const float*)d_in[6];
    p.bai = (const float*)d_in[7];
    p.Waj = (const float*)d_in[8];
    p.baj = (const float*)d_in[9];
    p.Wn  = (const float*)d_in[10];
    p.bn  = (const float*)d_in[11];
    p.Wo  = (const float*)d_in[12];
    p.bo  = (const float*)d_in[13];
    p.out = (float*)d_out;

    p.bar  = (int*)d_ws;                          // 4 ints (16B, keeps align)
    p.PQ   = (float*)d_ws + 4;                    // 800*64 f32
    p.Abuf = (short*)(p.PQ + 800 * 64);           // 800*320 bf16
    p.W2T  = p.Abuf + T_ABUF;                     // 64*320
    p.WnT  = p.W2T + T_W2T;                       // 256*320
    p.WoT  = p.WnT + T_WNT;                       // 1440*256
    p.XN16 = p.WoT + T_WOT;                       // 800*256

    k_zero <<<1, 64, 0, stream>>>(p.bar);
    k_fused<<<GRID_, TPB_, 0, stream>>>(p);
}

// Round 11
// 238.569 us; speedup vs baseline: 2.2162x; 2.2162x over previous
//
#include <hip/hip_runtime.h>
#include <math.h>

#define B_ 2
#define N_ 400
#define F_ 246
#define C_ 32
#define LBL_ 1440

#define KX_ 320   // concat row: 246 x | 32 aggi | 32 aggj | 10 zero-pad
#define KN_ 256   // XNEW padded 246 -> 256

#define GRID_ 512 // exactly 2 blocks/CU x 256 CU (launch_bounds guarantees fit)
#define TPB_  256

#define T_ABUF (800 * KX_)
#define T_W2T  (64 * KX_)
#define T_WNT  (256 * KX_)
#define T_WOT  (LBL_ * KN_)

// Barrier: 512 flags, one per 64B line; generation values MAGIC+it+1.
// 0xAA poison never equals a target -> no init kernel needed; exact-match
// monotone generations are self-correcting across launches.
#define MAGIC_  0x5AB10000
#define FSTRIDE 16          // ints -> 64 B between flags

typedef __attribute__((ext_vector_type(8))) short bf16x8;  // 8 bf16, 4 VGPRs
typedef __attribute__((ext_vector_type(4))) float f32x4;

__device__ __forceinline__ short f2bf(float f) {           // RNE fp32->bf16
    unsigned u = __float_as_uint(f);
    return (short)((u + 0x7FFF + ((u >> 16) & 1)) >> 16);
}

struct KP {
    const float *x, *a, *e, *Ws, *bs, *al, *Wai, *bai, *Waj, *baj, *Wn, *bn, *Wo, *bo;
    float *out, *PQ;
    short *Abuf, *W2T, *WnT, *WoT, *XN16;
    int *flags;   // [512 * FSTRIDE]
    int *gen;     // 1 int, own line
};

// Flag-tree grid barrier: NO atomic RMW, no shared hot line between
// arrivals. Arrive = release-store own padded flag; block 0 sweeps all
// flags (relaxed, 2/thread), acquire-fence, release-stores gen; waiters
// spin relaxed on gen then acquire-fence. hb chain: writer data -> flag
// release -> block0 fence -> gen release -> waiter fence -> reads.
__device__ __forceinline__ void gbar(int* flags, int* gen, int it) {
    int target = MAGIC_ + it + 1;
    __syncthreads();
    if (blockIdx.x == 0) {
        if (threadIdx.x == 0)
            __hip_atomic_store(&flags[0], target, __ATOMIC_RELEASE,
                               __HIP_MEMORY_SCOPE_AGENT);
        int f1 = threadIdx.x * FSTRIDE;
        int f2 = (threadIdx.x + 256) * FSTRIDE;
        while (__hip_atomic_load(&flags[f1], __ATOMIC_RELAXED,
                                 __HIP_MEMORY_SCOPE_AGENT) != target)
            __builtin_amdgcn_s_sleep(1);
        while (__hip_atomic_load(&flags[f2], __ATOMIC_RELAXED,
                                 __HIP_MEMORY_SCOPE_AGENT) != target)
            __builtin_amdgcn_s_sleep(1);
        __builtin_amdgcn_fence(__ATOMIC_ACQUIRE, "agent");
        __syncthreads();
        if (threadIdx.x == 0)
            __hip_atomic_store(gen, target, __ATOMIC_RELEASE,
                               __HIP_MEMORY_SCOPE_AGENT);
    } else {
        if (threadIdx.x == 0) {
            __hip_atomic_store(&flags[blockIdx.x * FSTRIDE], target,
                               __ATOMIC_RELEASE, __HIP_MEMORY_SCOPE_AGENT);
            while (__hip_atomic_load(gen, __ATOMIC_RELAXED,
                                     __HIP_MEMORY_SCOPE_AGENT) != target)
                __builtin_amdgcn_s_sleep(1);
            __builtin_amdgcn_fence(__ATOMIC_ACQUIRE, "agent");
        }
        __syncthreads();
    }
}

// 16x16 MFMA tile: C = A[m0:+16,:K] * BT[n0:+16,:K]^T. Row-major bf16,
// K mult of 32. Layouts (HW-verified m89/m120): A[m=lane&15][k=quad*8+j];
// BT row n, consecutive k -> one 16B load; C/D col=lane&15, row=quad*4+reg.
template <int K>
__device__ __forceinline__ f32x4 mfma_tile(const short* __restrict__ A,
                                           const short* __restrict__ BT,
                                           int m0, int n0, int lane) {
    int r = lane & 15, quad = lane >> 4;
    const short* ap = A + (size_t)(m0 + r) * K + quad * 8;
    const short* bp = BT + (size_t)(n0 + r) * K + quad * 8;
    f32x4 acc = {0.f, 0.f, 0.f, 0.f};
    #pragma unroll
    for (int kk = 0; kk < K; kk += 32) {
        bf16x8 av = *(const bf16x8*)(ap + kk);
        bf16x8 bv = *(const bf16x8*)(bp + kk);
        acc = __builtin_amdgcn_mfma_f32_16x16x32_bf16(av, bv, acc, 0, 0, 0);
    }
    return acc;
}

__global__ __launch_bounds__(TPB_, 2) void k_fused(KP p) {
    int tid  = threadIdx.x;
    int gt   = blockIdx.x * TPB_ + tid;       // global thread id
    int wv   = gt >> 6;                       // global wave id
    int lane = tid & 63;
    const int NT = GRID_ * TPB_;              // 131072 threads
    const int NW = NT / 64;                   // 2048 waves

    // ---- phase 1: bf16 staging (reads coalesced; 2B writes fire-and-forget)
    for (int t = gt; t < T_ABUF; t += NT) {   // Abuf[800][320] x-part + pad
        int row = t / KX_, k = t % KX_;
        p.Abuf[t] = (k < F_) ? f2bf(p.x[row * F_ + k]) : (short)0;
    }
    for (int t = gt; t < T_W2T; t += NT) {    // W2T[64][320]
        int n = t & 63, k = t >> 6;           // n fast -> coalesced Ws read
        float v = 0.f;
        if (k < F_) v = (n < C_) ? p.Ws[k * C_ + n] : p.Ws[(F_ + k) * C_ + (n - C_)];
        p.W2T[(size_t)n * KX_ + k] = f2bf(v);
    }
    for (int t = gt; t < T_WNT; t += NT) {    // WnT[256][320]
        int n = t & 255, k = t >> 8;          // n fast -> coalesced Wn read
        float v = (n < F_ && k < F_ + 2 * C_) ? p.Wn[k * F_ + n] : 0.f;
        p.WnT[(size_t)n * KX_ + k] = f2bf(v);
    }
    for (int t = gt; t < T_WOT; t += NT) {    // WoT[1440][256]
        int n = t % LBL_, k = t / LBL_;       // n fast -> coalesced Wo read
        p.WoT[(size_t)n * KN_ + k] = (k < F_) ? f2bf(p.Wo[k * LBL_ + n]) : (short)0;
    }
    gbar(p.flags, p.gen, 0);

    // ---- phase 2: PQ[800][64] = x @ [WsP | WsQ]  (fp32) ------------------
    for (int t = wv; t < 50 * 4; t += NW) {
        int m0 = (t % 50) * 16, n0 = (t / 50) * 16;
        f32x4 acc = mfma_tile<KX_>(p.Abuf, p.W2T, m0, n0, lane);
        int n = n0 + (lane & 15), mb = m0 + (lane >> 4) * 4;
        #pragma unroll
        for (int r = 0; r < 4; ++r)
            p.PQ[(size_t)(mb + r) * 64 + n] = acc[r];
    }
    gbar(p.flags, p.gen, 1);

    // ---- phase 3: aggregation (sparse, fp32 VALU) -> bf16 agg cols of Abuf
    {
        __shared__ float part[8][C_ + 1];
        int c = tid & 31, g = tid >> 5;
        for (int v = blockIdx.x; v < 2 * B_ * N_; v += GRID_) {
            int mode = (v >= B_ * N_) ? 1 : 0;
            int row  = mode ? v - B_ * N_ : v;
            int b = row / N_, n = row % N_;

            float w3  = p.Ws[(2 * F_) * C_ + c];
            float w4  = p.Ws[(2 * F_ + 1) * C_ + c];
            float bsc = p.bs[c];
            float alc = p.al[c];
            float wat = mode ? p.Waj[c] : p.Wai[c];
            float bat = mode ? p.baj[0] : p.bai[0];

            float ownc = p.PQ[(size_t)row * 64 + (mode ? 32 : 0) + c];
            const float* oth = p.PQ + (size_t)b * N_ * 64 + (mode ? 0 : 32) + c;
            const float* abase = p.a + (size_t)b * N_ * N_;
            const float* ebase = p.e + (size_t)b * N_ * N_;

            float acc = 0.f;
            #pragma unroll 4
            for (int m = g; m < N_; m += 8) {
                float aij  = mode ? abase[m * N_ + n] : abase[n * N_ + m];
                float er   = ebase[n * N_ + m];
                float ec   = ebase[m * N_ + n];
                float othv = oth[(size_t)m * 64];
                if (aij != 0.f) {                 // uniform per 32-lane group
                    float eij = mode ? ec : er;
                    float eji = mode ? er : ec;
                    float raw = ownc + othv + eij * w3 + eji * w4 + bsc;
                    float s = (raw >= 0.f ? raw : alc * raw) * aij;
                    float t2 = s * wat;           // 32-ch butterfly dot
                    t2 += __shfl_xor(t2, 1, 32);
                    t2 += __shfl_xor(t2, 2, 32);
                    t2 += __shfl_xor(t2, 4, 32);
                    t2 += __shfl_xor(t2, 8, 32);
                    t2 += __shfl_xor(t2, 16, 32);
                    float att = 1.f / (1.f + __expf(-(t2 + bat)));
                    acc += s * att;
                }
            }
            part[g][c] = acc;
            __syncthreads();
            if (tid < C_) {
                float tot = 0.f;
                #pragma unroll
                for (int gg = 0; gg < 8; ++gg) tot += part[gg][tid];
                // Abuf agg cols: mode 0 -> 246..277 (agg_i), 1 -> 278..309
                p.Abuf[(size_t)row * KX_ + F_ + mode * C_ + tid] = f2bf(tot);
            }
            __syncthreads();
        }
    }
    gbar(p.flags, p.gen, 2);

    // ---- phase 4: XN16[800][256] = bf16(Abuf @ WnT^T + bn) ---------------
    for (int t = wv; t < 50 * 16; t += NW) {
        int m0 = (t % 50) * 16, n0 = (t / 50) * 16;
        f32x4 acc = mfma_tile<KX_>(p.Abuf, p.WnT, m0, n0, lane);
        int n = n0 + (lane & 15), mb = m0 + (lane >> 4) * 4;
        float bv = (n < F_) ? p.bn[n] : 0.f;
        #pragma unroll
        for (int r = 0; r < 4; ++r)
            p.XN16[(size_t)(mb + r) * KN_ + n] =
                (n < F_) ? f2bf(acc[r] + bv) : (short)0;
    }
    gbar(p.flags, p.gen, 3);

    // ---- phase 5: out[800][1440] = XN16 @ WoT^T + bo  (fp32) -------------
    for (int t = wv; t < 50 * 90; t += NW) {
        int m0 = (t % 50) * 16, n0 = (t / 50) * 16;
        f32x4 acc = mfma_tile<KN_>(p.XN16, p.WoT, m0, n0, lane);
        int n = n0 + (lane & 15), mb = m0 + (lane >> 4) * 4;
        float bv = p.bo[n];
        #pragma unroll
        for (int r = 0; r < 4; ++r)
            p.out[(size_t)(mb + r) * LBL_ + n] = acc[r] + bv;
    }
}

// ---------------------------------------------------------------------------
extern "C" void kernel_launch(void* const* d_in, const int* in_sizes, int n_in,
                              void* d_out, int out_size, void* d_ws, size_t ws_size,
                              hipStream_t stream) {
    KP p;
    p.x   = (const float*)d_in[0];
    p.a   = (const float*)d_in[1];
    p.e   = (const float*)d_in[2];
    p.Ws  = (const float*)d_in[3];
    p.bs  = (const float*)d_in[4];
    p.al  = (const float*)d_in[5];
    p.Wai = (const float*)d_in[6];
    p.bai = (const float*)d_in[7];
    p.Waj = (const float*)d_in[8];
    p.baj = (const float*)d_in[9];
    p.Wn  = (const float*)d_in[10];
    p.bn  = (const float*)d_in[11];
    p.Wo  = (const float*)d_in[12];
    p.bo  = (const float*)d_in[13];
    p.out = (float*)d_out;

    p.flags = (int*)d_ws;                          // 512 * 16 ints (32 KB)
    p.gen   = p.flags + GRID_ * FSTRIDE;           // own line
    p.PQ    = (float*)(p.gen + FSTRIDE);           // 800*64 f32
    p.Abuf  = (short*)(p.PQ + 800 * 64);           // 800*320 bf16
    p.W2T   = p.Abuf + T_ABUF;                     // 64*320
    p.WnT   = p.W2T + T_W2T;                       // 256*320
    p.WoT   = p.WnT + T_WNT;                       // 1440*256
    p.XN16  = p.WoT + T_WOT;                       // 800*256

    k_fused<<<GRID_, TPB_, 0, stream>>>(p);
}

// Round 12
// 126.524 us; speedup vs baseline: 4.1789x; 1.8856x over previous
//
#include <hip/hip_runtime.h>
#include <math.h>

#define B_ 2
#define N_ 400
#define F_ 246
#define C_ 32
#define LBL_ 1440
#define NODE_IN_ 310  // F + 2C

#define KX_ 320   // concat row: 246 x | 32 aggi | 32 aggj | 10 pad (pad cols
                  // may hold poison: every consumer's weight there is 0.0)
#define KN_ 256   // XNEW padded 246 -> 256

#define T_ABUF (800 * KX_)
#define T_W2T  (64 * KX_)
#define T_WNT  (256 * KX_)
#define T_WOT  (LBL_ * KN_)

typedef __attribute__((ext_vector_type(8))) short bf16x8;  // 8 bf16, 4 VGPRs
typedef __attribute__((ext_vector_type(4))) float f32x4;

__device__ __forceinline__ short f2bf(float f) {           // RNE fp32->bf16
    unsigned u = __float_as_uint(f);
    return (short)((u + 0x7FFF + ((u >> 16) & 1)) >> 16);
}

// ---------------------------------------------------------------------------
// PREP (one dispatch, block ranges). All transposes LDS-tiled: coalesced
// reads AND writes (R7 had strided reads; R10/11 strided 2B writes = RMW).
//   blocks [0,800):        Abuf[row][0:246] = bf16(x row)   (pad cols unwritten)
//   blocks [800,1160):     WoT[1440][256] = bf16(Wo^T), 45x8 32x32 tiles
//   blocks [1160,1240):    WnT[256][320]  = bf16(Wn^T) zero-padded, 8x10 tiles
//   blocks [1240,1320):    W2T[64][320]   = [WsP|WsQ]^T zero-padded, linear
// ---------------------------------------------------------------------------
__global__ void k_prep(const float* __restrict__ x, const float* __restrict__ Ws,
                       const float* __restrict__ Wn, const float* __restrict__ Wo,
                       short* __restrict__ Abuf, short* __restrict__ W2T,
                       short* __restrict__ WnT, short* __restrict__ WoT) {
    __shared__ short tile[32][33];
    int bx = blockIdx.x, tid = threadIdx.x;
    if (bx < 800) {
        if (tid < F_) Abuf[bx * KX_ + tid] = f2bf(x[bx * F_ + tid]);
        return;
    }
    bx -= 800;
    int tx = tid & 31, ty = tid >> 5;      // 32 x 8
    if (bx < 360) {                        // WoT[n][k] = Wo[k][n]
        int n0 = (bx % 45) * 32, k0 = (bx / 45) * 32;
        #pragma unroll
        for (int r = 0; r < 4; ++r) {
            int k = k0 + ty + r * 8;
            tile[ty + r * 8][tx] = (k < F_) ? f2bf(Wo[k * LBL_ + n0 + tx]) : (short)0;
        }
        __syncthreads();
        #pragma unroll
        for (int r = 0; r < 4; ++r)
            WoT[(size_t)(n0 + ty + r * 8) * KN_ + k0 + tx] = tile[tx][ty + r * 8];
        return;
    }
    bx -= 360;
    if (bx < 80) {                         // WnT[n][k] = Wn[k][n] (zero-padded)
        int n0 = (bx % 8) * 32, k0 = (bx / 8) * 32;
        #pragma unroll
        for (int r = 0; r < 4; ++r) {
            int k = k0 + ty + r * 8, n = n0 + tx;
            tile[ty + r * 8][tx] =
                (n < F_ && k < NODE_IN_) ? f2bf(Wn[k * F_ + n]) : (short)0;
        }
        __syncthreads();
        #pragma unroll
        for (int r = 0; r < 4; ++r)
            WnT[(size_t)(n0 + ty + r * 8) * KX_ + k0 + tx] = tile[tx][ty + r * 8];
        return;
    }
    bx -= 80;
    {                                      // W2T linear (20480 elems)
        int t = bx * 256 + tid;
        if (t < 64 * KX_) {
            int n = t / KX_, k = t - n * KX_;
            float v = 0.f;
            if (k < F_) v = (n < C_) ? Ws[k * C_ + n] : Ws[(F_ + k) * C_ + (n - C_)];
            W2T[t] = f2bf(v);
        }
    }
}

// ---------------------------------------------------------------------------
// MFMA helpers. Layouts (HW-verified m89/m120): A[m=lane&15][k=quad*8+j];
// BT row-major [n][k]; C/D col=lane&15, row=quad*4+reg.
// ---------------------------------------------------------------------------
template <int K>
__device__ __forceinline__ f32x4 mfma_tile(const short* __restrict__ A,
                                           const short* __restrict__ BT,
                                           int m0, int n0, int lane) {
    int r = lane & 15, quad = lane >> 4;
    const short* ap = A + (size_t)(m0 + r) * K + quad * 8;
    const short* bp = BT + (size_t)(n0 + r) * K + quad * 8;
    f32x4 acc = {0.f, 0.f, 0.f, 0.f};
    #pragma unroll
    for (int kk = 0; kk < K; kk += 32) {
        bf16x8 av = *(const bf16x8*)(ap + kk);
        bf16x8 bv = *(const bf16x8*)(bp + kk);
        acc = __builtin_amdgcn_mfma_f32_16x16x32_bf16(av, bv, acc, 0, 0, 0);
    }
    return acc;
}

// Two n-tiles sharing one A-fragment: -25% loads, 2 independent acc chains.
template <int K>
__device__ __forceinline__ void mfma_tile2(const short* __restrict__ A,
                                           const short* __restrict__ BT,
                                           int m0, int n0, int lane,
                                           f32x4& acc0, f32x4& acc1) {
    int r = lane & 15, quad = lane >> 4;
    const short* ap = A + (size_t)(m0 + r) * K + quad * 8;
    const short* b0 = BT + (size_t)(n0 + r) * K + quad * 8;
    const short* b1 = BT + (size_t)(n0 + 16 + r) * K + quad * 8;
    #pragma unroll
    for (int kk = 0; kk < K; kk += 32) {
        bf16x8 av  = *(const bf16x8*)(ap + kk);
        bf16x8 bv0 = *(const bf16x8*)(b0 + kk);
        bf16x8 bv1 = *(const bf16x8*)(b1 + kk);
        acc0 = __builtin_amdgcn_mfma_f32_16x16x32_bf16(av, bv0, acc0, 0, 0, 0);
        acc1 = __builtin_amdgcn_mfma_f32_16x16x32_bf16(av, bv1, acc1, 0, 0, 0);
    }
}

// K1: PQ[800][64] = x @ [WsP|WsQ]  (fp32; Abuf pad cols x W2T zeros = 0)
__global__ void k_pq(const short* __restrict__ Abuf, const short* __restrict__ W2T,
                     float* __restrict__ PQ) {
    int lane = threadIdx.x;
    int m0 = blockIdx.x * 16, n0 = blockIdx.y * 16;
    f32x4 acc = mfma_tile<KX_>(Abuf, W2T, m0, n0, lane);
    int n = n0 + (lane & 15), mb = m0 + (lane >> 4) * 4;
    #pragma unroll
    for (int r = 0; r < 4; ++r)
        PQ[(size_t)(mb + r) * 64 + n] = acc[r];
}

// ---------------------------------------------------------------------------
// K2: aggregation (sparse, fp32 VALU) -> writes bf16 agg cols of Abuf.
// grid = 1600 blocks x 256 thr (8 groups x 32 lanes, lane = channel).
// ---------------------------------------------------------------------------
__global__ void k_agg(const float* __restrict__ a, const float* __restrict__ e,
                      const float* __restrict__ Ws, const float* __restrict__ bs,
                      const float* __restrict__ alpha,
                      const float* __restrict__ Wai, const float* __restrict__ bai,
                      const float* __restrict__ Waj, const float* __restrict__ baj,
                      const float* __restrict__ PQ, short* __restrict__ Abuf) {
    int blk  = blockIdx.x;
    int mode = (blk >= B_ * N_) ? 1 : 0;
    int row  = mode ? blk - B_ * N_ : blk;   // b*N + n
    int b = row / N_, n = row % N_;
    int tid = threadIdx.x;
    int c = tid & 31, g = tid >> 5;

    float w3  = Ws[(2 * F_) * C_ + c];
    float w4  = Ws[(2 * F_ + 1) * C_ + c];
    float bsc = bs[c];
    float alc = alpha[c];
    float wat = mode ? Waj[c] : Wai[c];
    float bat = mode ? baj[0] : bai[0];

    float ownc = PQ[(size_t)row * 64 + (mode ? 32 : 0) + c];
    const float* oth = PQ + (size_t)b * N_ * 64 + (mode ? 0 : 32) + c;
    const float* abase = a + (size_t)b * N_ * N_;
    const float* ebase = e + (size_t)b * N_ * N_;

    float acc = 0.f;
    #pragma unroll 4
    for (int m = g; m < N_; m += 8) {
        float aij  = mode ? abase[m * N_ + n] : abase[n * N_ + m];
        float er   = ebase[n * N_ + m];
        float ec   = ebase[m * N_ + n];
        float othv = oth[(size_t)m * 64];
        if (aij != 0.f) {                    // uniform per 32-lane group
            float eij = mode ? ec : er;
            float eji = mode ? er : ec;
            float raw = ownc + othv + eij * w3 + eji * w4 + bsc;
            float s = (raw >= 0.f ? raw : alc * raw) * aij;
            float t2 = s * wat;              // 32-ch butterfly dot
            t2 += __shfl_xor(t2, 1, 32);
            t2 += __shfl_xor(t2, 2, 32);
            t2 += __shfl_xor(t2, 4, 32);
            t2 += __shfl_xor(t2, 8, 32);
            t2 += __shfl_xor(t2, 16, 32);
            float att = 1.f / (1.f + __expf(-(t2 + bat)));
            acc += s * att;
        }
    }
    __shared__ float part[8][C_ + 1];
    part[g][c] = acc;
    __syncthreads();
    if (tid < C_) {
        float tot = 0.f;
        #pragma unroll
        for (int gg = 0; gg < 8; ++gg) tot += part[gg][tid];
        // Abuf agg cols: mode 0 -> 246..277 (agg_i), mode 1 -> 278..309
        Abuf[(size_t)row * KX_ + F_ + mode * C_ + tid] = f2bf(tot);
    }
}

// K3: XN16[800][256] = bf16(Abuf @ WnT^T + bn); 2 n-tiles/wave, grid (50,8)
__global__ void k_node(const short* __restrict__ Abuf, const short* __restrict__ WnT,
                       const float* __restrict__ bn, short* __restrict__ XN16) {
    int lane = threadIdx.x;
    int m0 = blockIdx.x * 16, n0 = blockIdx.y * 32;
    f32x4 a0 = {0,0,0,0}, a1 = {0,0,0,0};
    mfma_tile2<KX_>(Abuf, WnT, m0, n0, lane, a0, a1);
    int col = lane & 15, mb = m0 + (lane >> 4) * 4;
    #pragma unroll
    for (int h = 0; h < 2; ++h) {
        int nn = n0 + h * 16 + col;
        f32x4 acc = h ? a1 : a0;
        float bv = (nn < F_) ? bn[nn] : 0.f;
        #pragma unroll
        for (int r = 0; r < 4; ++r)
            XN16[(size_t)(mb + r) * KN_ + nn] =
                (nn < F_) ? f2bf(acc[r] + bv) : (short)0;
    }
}

// K4: out[800][1440] = XN16 @ WoT^T + bo; 2 n-tiles/wave, grid (50,45)
__global__ void k_out(const short* __restrict__ XN16, const short* __restrict__ WoT,
                      const float* __restrict__ bo, float* __restrict__ out) {
    int lane = threadIdx.x;
    int m0 = blockIdx.x * 16, n0 = blockIdx.y * 32;
    f32x4 a0 = {0,0,0,0}, a1 = {0,0,0,0};
    mfma_tile2<KN_>(XN16, WoT, m0, n0, lane, a0, a1);
    int col = lane & 15, mb = m0 + (lane >> 4) * 4;
    #pragma unroll
    for (int h = 0; h < 2; ++h) {
        int nn = n0 + h * 16 + col;
        f32x4 acc = h ? a1 : a0;
        float bv = bo[nn];
        #pragma unroll
        for (int r = 0; r < 4; ++r)
            out[(size_t)(mb + r) * LBL_ + nn] = acc[r] + bv;
    }
}

// ---------------------------------------------------------------------------
extern "C" void kernel_launch(void* const* d_in, const int* in_sizes, int n_in,
                              void* d_out, int out_size, void* d_ws, size_t ws_size,
                              hipStream_t stream) {
    const float* x   = (const float*)d_in[0];
    const float* a   = (const float*)d_in[1];
    const float* e   = (const float*)d_in[2];
    const float* Ws  = (const float*)d_in[3];
    const float* bs  = (const float*)d_in[4];
    const float* al  = (const float*)d_in[5];
    const float* Wai = (const float*)d_in[6];
    const float* bai = (const float*)d_in[7];
    const float* Waj = (const float*)d_in[8];
    const float* baj = (const float*)d_in[9];
    const float* Wn  = (const float*)d_in[10];
    const float* bn  = (const float*)d_in[11];
    const float* Wo  = (const float*)d_in[12];
    const float* bo  = (const float*)d_in[13];

    float* PQ   = (float*)d_ws;                   // 800*64 f32
    short* Abuf = (short*)(PQ + 800 * 64);        // 800*320 bf16 (16B-aligned)
    short* W2T  = Abuf + T_ABUF;                  // 64*320
    short* WnT  = W2T + T_W2T;                    // 256*320
    short* WoT  = WnT + T_WNT;                    // 1440*256
    short* XN16 = WoT + T_WOT;                    // 800*256

    k_prep<<<1320, 256, 0, stream>>>(x, Ws, Wn, Wo, Abuf, W2T, WnT, WoT);
    k_pq  <<<dim3(50, 4),  64, 0, stream>>>(Abuf, W2T, PQ);
    k_agg <<<2 * B_ * N_, 256, 0, stream>>>(a, e, Ws, bs, al, Wai, bai, Waj, baj,
                                            PQ, Abuf);
    k_node<<<dim3(50, 8),  64, 0, stream>>>(Abuf, WnT, bn, XN16);
    k_out <<<dim3(50, 45), 64, 0, stream>>>(XN16, WoT, bo, (float*)d_out);
}